// Round 1
// baseline (811.831 us; speedup 1.0000x reference)
//
#include <hip/hip_runtime.h>

// Problem: B=4, H=32, S=4096, T=1, D=128, fp32.
// out = concat(k_new, v_new) flat; k_new = [B,H,S+1,D] = k_cache rows then k_val row per (b,h).
//
// All in float4 units:
//   per-(b,h) cache chunk : S*D/4   = 4096*32 = 131072  (= 2^17)
//   per-(b,h) out chunk   : (S+1)*D/4 = 4097*32 = 131104
//   cache half size       : B*H * 2^17 = 128*131072 = 16777216 (= 2^24)
//   out half size         : 128*131104 = 16781312
//   val half size         : B*H * D/4 = 128*32 = 4096 (= 2^12)

#define BH        128        // B*H
#define CHUNK4    131072     // S*D/4 = 2^17
#define OUTCHUNK4 131104     // (S+1)*D/4
#define HALF4     16777216   // BH*CHUNK4 = 2^24
#define OUTHALF4  16781312   // BH*OUTCHUNK4
#define BULK4     33554432   // 2*HALF4
#define TAIL4     8192       // 2*BH*(D/4)

__global__ __launch_bounds__(256) void kv_append_kernel(
    const float4* __restrict__ kc, const float4* __restrict__ vc,
    const float4* __restrict__ kv, const float4* __restrict__ vv,
    float4* __restrict__ out)
{
    long idx = (long)blockIdx.x * blockDim.x + threadIdx.x;
    if (idx < BULK4) {
        // bulk: copy cache rows. All pow-2 shifts/masks.
        long half   = idx >> 24;           // 0 = k, 1 = v
        long rem    = idx & (HALF4 - 1);   // index into cache half
        long bh     = rem >> 17;           // which (b,h)
        long within = rem & (CHUNK4 - 1);  // float4 within chunk
        const float4* __restrict__ src = half ? vc : kc;
        float4 val = src[rem];
        out[half * (long)OUTHALF4 + bh * (long)OUTCHUNK4 + within] = val;
    } else {
        // tail: the appended T=1 row per (b,h).
        long t = idx - BULK4;
        if (t < TAIL4) {
            long half = t >> 12;           // 0 = k_val, 1 = v_val
            long rem  = t & 4095;          // index into val half (BH * D/4)
            long bh   = rem >> 5;          // which (b,h)
            long j    = rem & 31;          // float4 within the D=128 row
            const float4* __restrict__ src = half ? vv : kv;
            float4 val = src[rem];
            out[half * (long)OUTHALF4 + bh * (long)OUTCHUNK4 + CHUNK4 + j] = val;
        }
    }
}

extern "C" void kernel_launch(void* const* d_in, const int* in_sizes, int n_in,
                              void* d_out, int out_size, void* d_ws, size_t ws_size,
                              hipStream_t stream) {
    const float4* kc = (const float4*)d_in[0];
    const float4* vc = (const float4*)d_in[1];
    const float4* kv = (const float4*)d_in[2];
    const float4* vv = (const float4*)d_in[3];
    float4* out = (float4*)d_out;

    const long total = (long)BULK4 + TAIL4;          // 33,562,624 float4
    const int  block = 256;
    const long grid  = (total + block - 1) / block;  // 131,104 blocks

    kv_append_kernel<<<dim3((unsigned)grid), dim3(block), 0, stream>>>(kc, vc, kv, vv, out);
}